// Round 1
// baseline (3998.101 us; speedup 1.0000x reference)
//
#include <hip/hip_runtime.h>
#include <math.h>

#define T_STEPS 100
#define BATCH   32
#define EMB     256
#define HID     512
#define FEATC   1024
#define VOCAB   32000
#define GATES   2048   // 4*HID
#define M_ROWS  (T_STEPS * BATCH)   // 3200

// ---------------------------------------------------------------------------
// Kernel A: adaptive-avg-pool(7x7) + fc -> h0   (writes hbuf[0])
// ---------------------------------------------------------------------------
__global__ __launch_bounds__(512) void pool_fc_kernel(
    const float* __restrict__ features, const float* __restrict__ fc_w,
    const float* __restrict__ fc_b, float* __restrict__ h0) {
  __shared__ float pooled_s[FEATC];
  const int b = blockIdx.x;
  const int tid = threadIdx.x;
  const float* fb = features + (size_t)b * FEATC * 49;
  for (int f = tid; f < FEATC; f += 512) {
    const float* p = fb + f * 49;
    float s = 0.f;
#pragma unroll
    for (int i = 0; i < 49; ++i) s += p[i];
    pooled_s[f] = s / 49.0f;
  }
  __syncthreads();
  // one hidden unit per thread (512 threads)
  const float4* w4 = (const float4*)(fc_w + (size_t)tid * FEATC);
  const float4* p4 = (const float4*)pooled_s;
  float acc = fc_b[tid];
#pragma unroll 8
  for (int k = 0; k < FEATC / 4; ++k) {
    float4 w = w4[k], p = p4[k];
    acc += w.x * p.x + w.y * p.y + w.z * p.z + w.w * p.w;
  }
  h0[b * HID + tid] = acc;
}

// ---------------------------------------------------------------------------
// Kernel B: xg[m][col] = emb[tok[m]] @ W_ih.T + b_ih + b_hh
//   M=3200 (m = t*32+b), N=2048, K=256
// ---------------------------------------------------------------------------
#define BM 128
#define BN 128
#define BK 16
#define LDP (BM + 4)

__global__ __launch_bounds__(256) void xg_gemm_kernel(
    const int* __restrict__ reports, const float* __restrict__ emb,
    const float* __restrict__ W_ih, const float* __restrict__ b_ih,
    const float* __restrict__ b_hh, float* __restrict__ xg) {
  __shared__ float As[BK][LDP];
  __shared__ float Bs[BK][LDP];
  __shared__ int rowbase_s[BM];
  const int tid = threadIdx.x;
  const int n0 = blockIdx.x * BN;
  const int m0 = blockIdx.y * BM;
  if (tid < BM) {
    int m = m0 + tid;
    int t = m >> 5, b = m & 31;
    int tok = (t == 0) ? 1 : reports[b * T_STEPS + (t - 1)];
    rowbase_s[tid] = tok * EMB;
  }
  __syncthreads();

  float acc[8][8];
#pragma unroll
  for (int i = 0; i < 8; ++i)
#pragma unroll
    for (int j = 0; j < 8; ++j) acc[i][j] = 0.f;

  const int tx = tid & 15, ty = tid >> 4;

  for (int kt = 0; kt < EMB / BK; ++kt) {
    const int k0 = kt * BK;
#pragma unroll
    for (int l = 0; l < 2; ++l) {
      int idx = l * 256 + tid;          // [0,512)
      int rm = idx >> 2;                // row within tile [0,128)
      int kk = (idx & 3) * 4;           // k offset {0,4,8,12}
      float4 av = *(const float4*)(emb + rowbase_s[rm] + k0 + kk);
      As[kk + 0][rm] = av.x; As[kk + 1][rm] = av.y;
      As[kk + 2][rm] = av.z; As[kk + 3][rm] = av.w;
      float4 bvv = *(const float4*)(W_ih + (size_t)(n0 + rm) * EMB + k0 + kk);
      Bs[kk + 0][rm] = bvv.x; Bs[kk + 1][rm] = bvv.y;
      Bs[kk + 2][rm] = bvv.z; Bs[kk + 3][rm] = bvv.w;
    }
    __syncthreads();
#pragma unroll
    for (int kk = 0; kk < BK; ++kk) {
      float a[8], bf[8];
      *(float4*)(a)     = *(const float4*)&As[kk][ty * 4];
      *(float4*)(a + 4) = *(const float4*)&As[kk][64 + ty * 4];
      *(float4*)(bf)     = *(const float4*)&Bs[kk][tx * 4];
      *(float4*)(bf + 4) = *(const float4*)&Bs[kk][64 + tx * 4];
#pragma unroll
      for (int i = 0; i < 8; ++i)
#pragma unroll
        for (int j = 0; j < 8; ++j) acc[i][j] += a[i] * bf[j];
    }
    __syncthreads();
  }

#pragma unroll
  for (int i = 0; i < 8; ++i) {
    int m = m0 + ((i < 4) ? (ty * 4 + i) : (64 + ty * 4 + i - 4));
    float* orow = xg + (size_t)m * GATES;
    int c0 = n0 + tx * 4;
    int c1 = n0 + 64 + tx * 4;
    float4 r0, r1;
    r0.x = acc[i][0] + b_ih[c0 + 0] + b_hh[c0 + 0];
    r0.y = acc[i][1] + b_ih[c0 + 1] + b_hh[c0 + 1];
    r0.z = acc[i][2] + b_ih[c0 + 2] + b_hh[c0 + 2];
    r0.w = acc[i][3] + b_ih[c0 + 3] + b_hh[c0 + 3];
    r1.x = acc[i][4] + b_ih[c1 + 0] + b_hh[c1 + 0];
    r1.y = acc[i][5] + b_ih[c1 + 1] + b_hh[c1 + 1];
    r1.z = acc[i][6] + b_ih[c1 + 2] + b_hh[c1 + 2];
    r1.w = acc[i][7] + b_ih[c1 + 3] + b_hh[c1 + 3];
    *(float4*)(orow + c0) = r0;
    *(float4*)(orow + c1) = r1;
  }
}

// ---------------------------------------------------------------------------
// Kernel C: one LSTM step.  grid = 256 blocks x 256 threads.
//   block: j = blockIdx&31 -> hidden units [16j,16j+16);  bg = blockIdx>>5 -> batches [4bg,4bg+4)
//   thread tid = u + 16*g + 64*b : one gate dot-product of length 512
// ---------------------------------------------------------------------------
__global__ __launch_bounds__(256) void lstm_step_kernel(
    const float* __restrict__ W_hh, const float* __restrict__ xg,
    float* __restrict__ hbuf, float* __restrict__ c_ws,
    float* __restrict__ Hall, int t) {
  __shared__ float gsm[256];
  const int tid = threadIdx.x;
  const int j  = blockIdx.x & 31;
  const int bg = blockIdx.x >> 5;
  const int u = tid & 15;
  const int g = (tid >> 4) & 3;
  const int b = tid >> 6;
  const int uu = j * 16 + u;
  const int row = g * HID + uu;
  const int bb = bg * 4 + b;

  const float4* h4 = (const float4*)(hbuf + (t & 1) * (BATCH * HID) + bb * HID);
  const float4* w4 = (const float4*)(W_hh + (size_t)row * HID);
  float acc = xg[((size_t)t * BATCH + bb) * GATES + row];
#pragma unroll 8
  for (int k = 0; k < HID / 4; ++k) {
    float4 hv = h4[k], wv = w4[k];
    acc += hv.x * wv.x + hv.y * wv.y + hv.z * wv.z + hv.w * wv.w;
  }
  gsm[tid] = acc;
  __syncthreads();
  if (tid < 64) {
    const int u2 = tid & 15, b2 = tid >> 4;
    const int bb2 = bg * 4 + b2;
    const int uu2 = j * 16 + u2;
    float iv = gsm[b2 * 64 + 0 * 16 + u2];
    float fv = gsm[b2 * 64 + 1 * 16 + u2];
    float gv = gsm[b2 * 64 + 2 * 16 + u2];
    float ov = gsm[b2 * 64 + 3 * 16 + u2];
    float si = 1.f / (1.f + expf(-iv));
    float sf = 1.f / (1.f + expf(-fv));
    float sg = tanhf(gv);
    float so = 1.f / (1.f + expf(-ov));
    int cidx = bb2 * HID + uu2;
    float cp = (t == 0) ? 0.f : c_ws[cidx];
    float cn = sf * cp + si * sg;
    float hn = so * tanhf(cn);
    c_ws[cidx] = cn;
    hbuf[((t + 1) & 1) * (BATCH * HID) + cidx] = hn;
    Hall[((size_t)t * BATCH + bb2) * HID + uu2] = hn;
  }
}

// ---------------------------------------------------------------------------
// Kernel D: logits = Hall @ Wv.T + bv ;  M=3200, N=32000, K=512
//   output written as out[b][t][v]  (row m = t*32+b)
// ---------------------------------------------------------------------------
__global__ __launch_bounds__(256) void out_gemm_kernel(
    const float* __restrict__ Hall, const float* __restrict__ Wv,
    const float* __restrict__ bv, float* __restrict__ out) {
  __shared__ float As[BK][LDP];
  __shared__ float Bs[BK][LDP];
  const int tid = threadIdx.x;
  const int n0 = blockIdx.x * BN;
  const int m0 = blockIdx.y * BM;

  float acc[8][8];
#pragma unroll
  for (int i = 0; i < 8; ++i)
#pragma unroll
    for (int j = 0; j < 8; ++j) acc[i][j] = 0.f;

  const int tx = tid & 15, ty = tid >> 4;

  for (int kt = 0; kt < HID / BK; ++kt) {
    const int k0 = kt * BK;
#pragma unroll
    for (int l = 0; l < 2; ++l) {
      int idx = l * 256 + tid;
      int rm = idx >> 2;
      int kk = (idx & 3) * 4;
      float4 av = *(const float4*)(Hall + (size_t)(m0 + rm) * HID + k0 + kk);
      As[kk + 0][rm] = av.x; As[kk + 1][rm] = av.y;
      As[kk + 2][rm] = av.z; As[kk + 3][rm] = av.w;
      float4 bvv = *(const float4*)(Wv + (size_t)(n0 + rm) * HID + k0 + kk);
      Bs[kk + 0][rm] = bvv.x; Bs[kk + 1][rm] = bvv.y;
      Bs[kk + 2][rm] = bvv.z; Bs[kk + 3][rm] = bvv.w;
    }
    __syncthreads();
#pragma unroll
    for (int kk = 0; kk < BK; ++kk) {
      float a[8], bf[8];
      *(float4*)(a)     = *(const float4*)&As[kk][ty * 4];
      *(float4*)(a + 4) = *(const float4*)&As[kk][64 + ty * 4];
      *(float4*)(bf)     = *(const float4*)&Bs[kk][tx * 4];
      *(float4*)(bf + 4) = *(const float4*)&Bs[kk][64 + tx * 4];
#pragma unroll
      for (int i = 0; i < 8; ++i)
#pragma unroll
        for (int j = 0; j < 8; ++j) acc[i][j] += a[i] * bf[j];
    }
    __syncthreads();
  }

  const int c0 = n0 + tx * 4;
  const int c1 = n0 + 64 + tx * 4;
  float4 bv0 = *(const float4*)(bv + c0);
  float4 bv1 = *(const float4*)(bv + c1);
#pragma unroll
  for (int i = 0; i < 8; ++i) {
    int m = m0 + ((i < 4) ? (ty * 4 + i) : (64 + ty * 4 + i - 4));
    int t = m >> 5, b = m & 31;
    float* orow = out + ((size_t)b * T_STEPS + t) * VOCAB;
    float4 r0, r1;
    r0.x = acc[i][0] + bv0.x; r0.y = acc[i][1] + bv0.y;
    r0.z = acc[i][2] + bv0.z; r0.w = acc[i][3] + bv0.w;
    r1.x = acc[i][4] + bv1.x; r1.y = acc[i][5] + bv1.y;
    r1.z = acc[i][6] + bv1.z; r1.w = acc[i][7] + bv1.w;
    *(float4*)(orow + c0) = r0;
    *(float4*)(orow + c1) = r1;
  }
}

// ---------------------------------------------------------------------------
extern "C" void kernel_launch(void* const* d_in, const int* in_sizes, int n_in,
                              void* d_out, int out_size, void* d_ws, size_t ws_size,
                              hipStream_t stream) {
  const float* features = (const float*)d_in[0];
  const int*   reports  = (const int*)d_in[1];
  const float* emb      = (const float*)d_in[2];
  const float* fc_w     = (const float*)d_in[3];
  const float* fc_b     = (const float*)d_in[4];
  const float* W_ih     = (const float*)d_in[5];
  const float* b_ih     = (const float*)d_in[6];
  const float* W_hh     = (const float*)d_in[7];
  const float* b_hh     = (const float*)d_in[8];
  const float* Wv       = (const float*)d_in[9];
  const float* bv       = (const float*)d_in[10];
  float* out = (float*)d_out;

  float* ws   = (float*)d_ws;
  float* xg   = ws;                                   // 3200*2048
  float* hbuf = xg + (size_t)M_ROWS * GATES;          // 2*32*512
  float* c_ws = hbuf + 2 * BATCH * HID;               // 32*512
  float* Hall = c_ws + BATCH * HID;                   // 3200*512

  pool_fc_kernel<<<BATCH, 512, 0, stream>>>(features, fc_w, fc_b, hbuf);
  xg_gemm_kernel<<<dim3(GATES / BN, M_ROWS / BM), 256, 0, stream>>>(
      reports, emb, W_ih, b_ih, b_hh, xg);
  for (int t = 0; t < T_STEPS; ++t)
    lstm_step_kernel<<<256, 256, 0, stream>>>(W_hh, xg, hbuf, c_ws, Hall, t);
  out_gemm_kernel<<<dim3(VOCAB / BN, M_ROWS / BM), 256, 0, stream>>>(
      Hall, Wv, bv, out);
}

// Round 2
// 1761.516 us; speedup vs baseline: 2.2697x; 2.2697x over previous
//
#include <hip/hip_runtime.h>
#include <math.h>

#define T_STEPS 100
#define BATCH   32
#define EMB     256
#define HID     512
#define FEATC   1024
#define VOCAB   32000
#define GATES   2048   // 4*HID
#define M_ROWS  (T_STEPS * BATCH)   // 3200

typedef __attribute__((ext_vector_type(8))) short bf16x8;
typedef __attribute__((ext_vector_type(4))) float f32x4;
typedef unsigned short ushort_t;

__device__ __forceinline__ unsigned short f2bf(float x) {
  union { float f; unsigned u; } v; v.f = x;
  unsigned r = v.u + 0x7fff + ((v.u >> 16) & 1);
  return (unsigned short)(r >> 16);
}
__device__ __forceinline__ float bf2f(unsigned short h) {
  union { float f; unsigned u; } v; v.u = ((unsigned)h) << 16;
  return v.f;
}

// ---------------------------------------------------------------------------
// Kernel A: adaptive-avg-pool(7x7) + fc -> h0   (writes hbuf slot 0)
// ---------------------------------------------------------------------------
__global__ __launch_bounds__(512) void pool_fc_kernel(
    const float* __restrict__ features, const float* __restrict__ fc_w,
    const float* __restrict__ fc_b, float* __restrict__ h0) {
  __shared__ float pooled_s[FEATC];
  const int b = blockIdx.x;
  const int tid = threadIdx.x;
  const float* fb = features + (size_t)b * FEATC * 49;
  for (int f = tid; f < FEATC; f += 512) {
    const float* p = fb + f * 49;
    float s = 0.f;
#pragma unroll
    for (int i = 0; i < 49; ++i) s += p[i];
    pooled_s[f] = s / 49.0f;
  }
  __syncthreads();
  const float4* w4 = (const float4*)(fc_w + (size_t)tid * FEATC);
  const float4* p4 = (const float4*)pooled_s;
  float acc = fc_b[tid];
#pragma unroll 8
  for (int k = 0; k < FEATC / 4; ++k) {
    float4 w = w4[k], p = p4[k];
    acc += w.x * p.x + w.y * p.y + w.z * p.z + w.w * p.w;
  }
  h0[b * HID + tid] = acc;
}

// ---------------------------------------------------------------------------
// Kernel B: xg[m][col] = emb[tok[m]] @ W_ih.T + b_ih + b_hh  (fp32 tile GEMM)
// ---------------------------------------------------------------------------
#define BM 128
#define BN 128
#define BK 16
#define LDP (BM + 4)

__global__ __launch_bounds__(256) void xg_gemm_kernel(
    const int* __restrict__ reports, const float* __restrict__ emb,
    const float* __restrict__ W_ih, const float* __restrict__ b_ih,
    const float* __restrict__ b_hh, float* __restrict__ xg) {
  __shared__ float As[BK][LDP];
  __shared__ float Bs[BK][LDP];
  __shared__ int rowbase_s[BM];
  const int tid = threadIdx.x;
  const int n0 = blockIdx.x * BN;
  const int m0 = blockIdx.y * BM;
  if (tid < BM) {
    int m = m0 + tid;
    int t = m >> 5, b = m & 31;
    int tok = (t == 0) ? 1 : reports[b * T_STEPS + (t - 1)];
    rowbase_s[tid] = tok * EMB;
  }
  __syncthreads();

  float acc[8][8];
#pragma unroll
  for (int i = 0; i < 8; ++i)
#pragma unroll
    for (int j = 0; j < 8; ++j) acc[i][j] = 0.f;

  const int tx = tid & 15, ty = tid >> 4;

  for (int kt = 0; kt < EMB / BK; ++kt) {
    const int k0 = kt * BK;
#pragma unroll
    for (int l = 0; l < 2; ++l) {
      int idx = l * 256 + tid;
      int rm = idx >> 2;
      int kk = (idx & 3) * 4;
      float4 av = *(const float4*)(emb + rowbase_s[rm] + k0 + kk);
      As[kk + 0][rm] = av.x; As[kk + 1][rm] = av.y;
      As[kk + 2][rm] = av.z; As[kk + 3][rm] = av.w;
      float4 bvv = *(const float4*)(W_ih + (size_t)(n0 + rm) * EMB + k0 + kk);
      Bs[kk + 0][rm] = bvv.x; Bs[kk + 1][rm] = bvv.y;
      Bs[kk + 2][rm] = bvv.z; Bs[kk + 3][rm] = bvv.w;
    }
    __syncthreads();
#pragma unroll
    for (int kk = 0; kk < BK; ++kk) {
      float a[8], bf[8];
      *(float4*)(a)     = *(const float4*)&As[kk][ty * 4];
      *(float4*)(a + 4) = *(const float4*)&As[kk][64 + ty * 4];
      *(float4*)(bf)     = *(const float4*)&Bs[kk][tx * 4];
      *(float4*)(bf + 4) = *(const float4*)&Bs[kk][64 + tx * 4];
#pragma unroll
      for (int i = 0; i < 8; ++i)
#pragma unroll
        for (int j = 0; j < 8; ++j) acc[i][j] += a[i] * bf[j];
    }
    __syncthreads();
  }

#pragma unroll
  for (int i = 0; i < 8; ++i) {
    int m = m0 + ((i < 4) ? (ty * 4 + i) : (64 + ty * 4 + i - 4));
    float* orow = xg + (size_t)m * GATES;
    int c0 = n0 + tx * 4;
    int c1 = n0 + 64 + tx * 4;
    float4 r0, r1;
    r0.x = acc[i][0] + b_ih[c0 + 0] + b_hh[c0 + 0];
    r0.y = acc[i][1] + b_ih[c0 + 1] + b_hh[c0 + 1];
    r0.z = acc[i][2] + b_ih[c0 + 2] + b_hh[c0 + 2];
    r0.w = acc[i][3] + b_ih[c0 + 3] + b_hh[c0 + 3];
    r1.x = acc[i][4] + b_ih[c1 + 0] + b_hh[c1 + 0];
    r1.y = acc[i][5] + b_ih[c1 + 1] + b_hh[c1 + 1];
    r1.z = acc[i][6] + b_ih[c1 + 2] + b_hh[c1 + 2];
    r1.w = acc[i][7] + b_ih[c1 + 3] + b_hh[c1 + 3];
    *(float4*)(orow + c0) = r0;
    *(float4*)(orow + c1) = r1;
  }
}

// ---------------------------------------------------------------------------
// Kernel S: split fp32 -> bf16 hi/lo (for Wv)
// ---------------------------------------------------------------------------
__global__ __launch_bounds__(256) void split_kernel(
    const float* __restrict__ x, unsigned short* __restrict__ hi,
    unsigned short* __restrict__ lo, int n4) {
  int i = blockIdx.x * 256 + threadIdx.x;
  if (i >= n4) return;
  float4 v = ((const float4*)x)[i];
  ushort4 h, l;
  h.x = f2bf(v.x); l.x = f2bf(v.x - bf2f(h.x));
  h.y = f2bf(v.y); l.y = f2bf(v.y - bf2f(h.y));
  h.z = f2bf(v.z); l.z = f2bf(v.z - bf2f(h.z));
  h.w = f2bf(v.w); l.w = f2bf(v.w - bf2f(h.w));
  ((ushort4*)hi)[i] = h;
  ((ushort4*)lo)[i] = l;
}

// ---------------------------------------------------------------------------
// Kernel C: one LSTM step.  grid = 256 blocks x 1024 threads (16 waves/CU).
//   block: j = blockIdx&31 -> units [16j,16j+16); bg = blockIdx>>5 -> batches [4bg,4bg+4)
//   thread tid = kq + 4*u + 64*g + 256*b : quarter-dot (128 MACs) of gate row
// ---------------------------------------------------------------------------
__global__ __launch_bounds__(1024) void lstm_step_kernel(
    const float* __restrict__ W_hh, const float* __restrict__ xg,
    float* __restrict__ hbuf, float* __restrict__ c_ws,
    unsigned short* __restrict__ Hall_hi, unsigned short* __restrict__ Hall_lo,
    int t) {
  __shared__ float hsm[4][HID];
  __shared__ float psum[1024];
  __shared__ float gsm[4][4][16];   // [b][gate][u]
  const int tid = threadIdx.x;
  const int j = blockIdx.x & 31;
  const int bg = blockIdx.x >> 5;

  // stage h for this block's 4 batches (8 KB)
  const float* hsrc = hbuf + (t & 1) * (BATCH * HID);
  if (tid < 512) {
    int b = tid >> 7, k4 = (tid & 127) * 4;
    *(float4*)&hsm[b][k4] = *(const float4*)&hsrc[(bg * 4 + b) * HID + k4];
  }
  __syncthreads();

  const int kq = tid & 3, u = (tid >> 2) & 15, g = (tid >> 6) & 3, b = tid >> 8;
  const int row = g * HID + j * 16 + u;
  const float* wrow = W_hh + (size_t)row * HID;
  float acc = 0.f;
#pragma unroll
  for (int it = 0; it < 32; ++it) {
    int k = it * 16 + kq * 4;
    float4 wv = *(const float4*)&wrow[k];
    float4 hv = *(const float4*)&hsm[b][k];
    acc += wv.x * hv.x + wv.y * hv.y + wv.z * hv.z + wv.w * hv.w;
  }
  psum[tid] = acc;
  __syncthreads();

  if (tid < 256) {
    int u2 = tid & 15, g2 = (tid >> 4) & 3, b2 = tid >> 6;
    int base = (b2 << 8) + (g2 << 6) + (u2 << 2);
    float s = psum[base] + psum[base + 1] + psum[base + 2] + psum[base + 3];
    int row2 = g2 * HID + j * 16 + u2;
    s += xg[((size_t)t * BATCH + bg * 4 + b2) * GATES + row2];
    gsm[b2][g2][u2] = s;
  }
  __syncthreads();

  if (tid < 64) {
    int u3 = tid & 15, b3 = tid >> 4;
    float iv = gsm[b3][0][u3];
    float fv = gsm[b3][1][u3];
    float gv = gsm[b3][2][u3];
    float ov = gsm[b3][3][u3];
    float si = 1.f / (1.f + expf(-iv));
    float sf = 1.f / (1.f + expf(-fv));
    float sg = tanhf(gv);
    float so = 1.f / (1.f + expf(-ov));
    int bb = bg * 4 + b3, uu = j * 16 + u3;
    int cidx = bb * HID + uu;
    float cp = (t == 0) ? 0.f : c_ws[cidx];
    float cn = sf * cp + si * sg;
    float hn = so * tanhf(cn);
    c_ws[cidx] = cn;
    hbuf[((t + 1) & 1) * (BATCH * HID) + cidx] = hn;
    unsigned short hhi = f2bf(hn);
    unsigned short hlo = f2bf(hn - bf2f(hhi));
    size_t hidx = ((size_t)t * BATCH + bb) * HID + uu;
    Hall_hi[hidx] = hhi;
    Hall_lo[hidx] = hlo;
  }
}

// ---------------------------------------------------------------------------
// Kernel D: logits = Hall @ Wv.T + bv via split-bf16 MFMA (3 passes, fp32 acc)
//   M=3200 (grid.x=25), N=32000 (grid.y=250), K=512.  BM=BN=128, BK=32.
//   256 threads = 4 waves in 2x2; each wave 64x64 = 4x4 tiles of 16x16x32.
//   LDS tiles staged with global_load_lds width=16; XOR slot swizzle to spread
//   ds_read_b128 bank groups (unswizzled would be 8-way conflicted).
// ---------------------------------------------------------------------------
__global__ __launch_bounds__(256, 2) void out_mfma_kernel(
    const unsigned short* __restrict__ Ahi, const unsigned short* __restrict__ Alo,
    const unsigned short* __restrict__ Bhi, const unsigned short* __restrict__ Blo,
    const float* __restrict__ bv, float* __restrict__ out) {
  __shared__ unsigned short Ah[128 * 32], Al[128 * 32], Bh[128 * 32], Bl[128 * 32];
  const int tid = threadIdx.x;
  const int lane = tid & 63;
  const int w = tid >> 6;
  const int wm = w & 1, wn = w >> 1;
  const int m0 = blockIdx.x * 128;
  const int n0 = blockIdx.y * 128;

  f32x4 acc[4][4] = {};

  const int srow4 = lane >> 2;                          // staging row-within-16
  const int skoff = ((lane & 3) ^ ((lane >> 3) & 3)) * 8;  // swizzled k-chunk

  for (int kt = 0; kt < 16; ++kt) {
    const int k0 = kt * 32;
#pragma unroll
    for (int issue = 0; issue < 2; ++issue) {
      const int r = w * 32 + issue * 16 + srow4;
      const size_t gA = (size_t)(m0 + r) * 512 + k0 + skoff;
      const size_t gB = (size_t)(n0 + r) * 512 + k0 + skoff;
      const int loff = (w * 32 + issue * 16) * 32;
      __builtin_amdgcn_global_load_lds(
          (const __attribute__((address_space(1))) void*)(Ahi + gA),
          (__attribute__((address_space(3))) void*)(Ah + loff), 16, 0, 0);
      __builtin_amdgcn_global_load_lds(
          (const __attribute__((address_space(1))) void*)(Alo + gA),
          (__attribute__((address_space(3))) void*)(Al + loff), 16, 0, 0);
      __builtin_amdgcn_global_load_lds(
          (const __attribute__((address_space(1))) void*)(Bhi + gB),
          (__attribute__((address_space(3))) void*)(Bh + loff), 16, 0, 0);
      __builtin_amdgcn_global_load_lds(
          (const __attribute__((address_space(1))) void*)(Blo + gB),
          (__attribute__((address_space(3))) void*)(Bl + loff), 16, 0, 0);
    }
    __syncthreads();

    bf16x8 ah[4], al[4], bh[4], bl[4];
    const int q = lane >> 4;                 // k-quad 0..3
    const int rl = lane & 15;
    const int slot = (q ^ ((rl >> 1) & 3)) * 8;
#pragma unroll
    for (int i = 0; i < 4; ++i) {
      int arow = wm * 64 + i * 16 + rl;
      ah[i] = *(const bf16x8*)&Ah[arow * 32 + slot];
      al[i] = *(const bf16x8*)&Al[arow * 32 + slot];
      int brow = wn * 64 + i * 16 + rl;
      bh[i] = *(const bf16x8*)&Bh[brow * 32 + slot];
      bl[i] = *(const bf16x8*)&Bl[brow * 32 + slot];
    }
#pragma unroll
    for (int i = 0; i < 4; ++i)
#pragma unroll
      for (int jj = 0; jj < 4; ++jj) {
        acc[i][jj] = __builtin_amdgcn_mfma_f32_16x16x32_bf16(ah[i], bh[jj], acc[i][jj], 0, 0, 0);
        acc[i][jj] = __builtin_amdgcn_mfma_f32_16x16x32_bf16(al[i], bh[jj], acc[i][jj], 0, 0, 0);
        acc[i][jj] = __builtin_amdgcn_mfma_f32_16x16x32_bf16(ah[i], bl[jj], acc[i][jj], 0, 0, 0);
      }
    __syncthreads();
  }

  // epilogue: D[m = (lane>>4)*4 + reg][n = lane&15]; out is (B,T,V), m = t*32+b
#pragma unroll
  for (int jj = 0; jj < 4; ++jj) {
    const int ncol = n0 + wn * 64 + jj * 16 + (lane & 15);
    const float bvn = bv[ncol];
#pragma unroll
    for (int i = 0; i < 4; ++i) {
      const int mbase = m0 + wm * 64 + i * 16 + (lane >> 4) * 4;
#pragma unroll
      for (int r = 0; r < 4; ++r) {
        const int m = mbase + r;
        const int t = m >> 5, b = m & 31;
        out[((size_t)(b * T_STEPS + t)) * VOCAB + ncol] = acc[i][jj][r] + bvn;
      }
    }
  }
}

// ---------------------------------------------------------------------------
extern "C" void kernel_launch(void* const* d_in, const int* in_sizes, int n_in,
                              void* d_out, int out_size, void* d_ws, size_t ws_size,
                              hipStream_t stream) {
  const float* features = (const float*)d_in[0];
  const int*   reports  = (const int*)d_in[1];
  const float* emb      = (const float*)d_in[2];
  const float* fc_w     = (const float*)d_in[3];
  const float* fc_b     = (const float*)d_in[4];
  const float* W_ih     = (const float*)d_in[5];
  const float* b_ih     = (const float*)d_in[6];
  const float* W_hh     = (const float*)d_in[7];
  const float* b_hh     = (const float*)d_in[8];
  const float* Wv       = (const float*)d_in[9];
  const float* bv       = (const float*)d_in[10];
  float* out = (float*)d_out;

  float* ws = (float*)d_ws;
  float* xg   = ws;                                    // 3200*2048 f32
  float* hbuf = xg + (size_t)M_ROWS * GATES;           // 2*32*512 f32
  float* c_ws = hbuf + 2 * BATCH * HID;                // 32*512 f32
  unsigned short* Hall_hi = (unsigned short*)(c_ws + BATCH * HID);  // 3200*512 bf16
  unsigned short* Hall_lo = Hall_hi + (size_t)M_ROWS * HID;
  unsigned short* Wv_hi   = Hall_lo + (size_t)M_ROWS * HID;         // 32000*512 bf16
  unsigned short* Wv_lo   = Wv_hi + (size_t)VOCAB * HID;

  pool_fc_kernel<<<BATCH, 512, 0, stream>>>(features, fc_w, fc_b, hbuf);
  xg_gemm_kernel<<<dim3(GATES / BN, M_ROWS / BM), 256, 0, stream>>>(
      reports, emb, W_ih, b_ih, b_hh, xg);
  {
    int n4 = VOCAB * HID / 4;
    split_kernel<<<(n4 + 255) / 256, 256, 0, stream>>>(Wv, Wv_hi, Wv_lo, n4);
  }
  for (int t = 0; t < T_STEPS; ++t)
    lstm_step_kernel<<<256, 1024, 0, stream>>>(W_hh, xg, hbuf, c_ws,
                                               Hall_hi, Hall_lo, t);
  out_mfma_kernel<<<dim3(M_ROWS / 128, VOCAB / 128), 256, 0, stream>>>(
      Hall_hi, Hall_lo, Wv_hi, Wv_lo, bv, out);
}